// Round 13
// baseline (189.138 us; speedup 1.0000x reference)
//
#include <hip/hip_runtime.h>
#include <math.h>

#define NPIX   131072      // 8*128*128
#define CCH    256
#define HW     16384       // 128*128
#define BSTR   4194304     // 256*16384 (features b-stride)
#define NUMC   21
#define KC     5376        // 21*256
#define NREP   16
#define NLB    512         // k_labels blocks

typedef __attribute__((ext_vector_type(8))) short bf16x8;   // 8 bf16 (4 VGPRs)
typedef __attribute__((ext_vector_type(4))) float f32x4;

static __device__ __forceinline__ uint f2bf(float x) {      // f32 -> bf16 bits, RTNE
    uint u = __builtin_bit_cast(uint, x);
    return (u + 0x7FFFu + ((u >> 16) & 1u)) >> 16;
}
static __device__ __forceinline__ uint ohv(int lbl, int cls, uint iv) {
    return (lbl == cls) ? iv : 0u;                          // onehot*invn as bf16 bits
}
static __device__ __forceinline__ float rsq_fast(float x) { // single v_rsq_f32
#if __has_builtin(__builtin_amdgcn_rsqf)
    return __builtin_amdgcn_rsqf(x);
#else
    return rsqrtf(x);
#endif
}
// pack hi16(x),hi16(y) -> one word (bf16 trunc pair)
static __device__ __forceinline__ uint bfpack_trunc(float x, float y) {
    return __builtin_amdgcn_perm(__builtin_bit_cast(uint, y),
                                 __builtin_bit_cast(uint, x), 0x07060302u);
}

// ------- kernel 1: pseudo labels + per-block counts + zero part buffers -------
__global__ __launch_bounds__(256) void k_labels(const int* __restrict__ labels,
                                                const float* __restrict__ outputs_old,
                                                int* __restrict__ lab,
                                                float* __restrict__ cntPart,
                                                float* __restrict__ partzero)
{
    __shared__ float cnt[NUMC];
    if (threadIdx.x < NUMC) cnt[threadIdx.x] = 0.f;
    __syncthreads();

    // zero this block's slice of partA/partO (172032 floats / 512 blocks = 336)
    {
        float* pz = partzero + blockIdx.x * 336;
        for (int i = threadIdx.x; i < 336; i += 256) pz[i] = 0.f;
    }

    int p = blockIdx.x * 256 + threadIdx.x;
    int b = p >> 14;
    int rem = p & 16383;
    int h = rem >> 7;
    int w = rem & 127;
    int ld = labels[b * 262144 + (h * 4) * 512 + (w * 4)];
    int out = ld;
    if (ld == 0) {
        const float* oo = outputs_old + (size_t)b * BSTR + (size_t)(h * 4) * 512 + (w * 4);
        float v0 = oo[0];
        float best = (v0 < 0.7f) ? 0.0f : v0;
        int bi = 0;
        #pragma unroll
        for (int c = 1; c < 16; ++c) {
            float v = oo[(size_t)c * 262144];
            v = (v < 0.7f) ? 0.0f : v;
            if (v > best) { best = v; bi = c; }   // strict > == first-occurrence argmax
        }
        out = bi;
    }
    lab[p] = out;
    unsafeAtomicAdd(&cnt[out], 1.0f);
    __syncthreads();
    if (threadIdx.x < 32)
        cntPart[blockIdx.x * 32 + threadIdx.x] =
            (threadIdx.x < NUMC) ? cnt[threadIdx.x] : 0.f;   // full overwrite, no pre-zero
}

// ---------------- kernel 2: barrier-free register-resident MFMA sums ---------
// 512 blocks x 4 waves; each WAVE is independent: 128 px in 4 iters of 32 px.
// Lane's global loads land directly in MFMA B-frag layout (ch=n*16+(l&15),
// px=(l>>4)*8+j). ssq wave-local (shfl), invn lane-local for the lane's own
// A-frag pixels. NO LDS data path, NO barriers in the stream (only epilogue).
__global__ __launch_bounds__(256, 2) void k_msum(const float* __restrict__ fa,
                                                 const float* __restrict__ fo,
                                                 const int* __restrict__ lab,
                                                 float* __restrict__ partA,
                                                 float* __restrict__ partO)
{
    __shared__ float accS[32 * 256];      // 32 KB, rows 21..31 stay zero

    const int t = threadIdx.x;
    const int w = t >> 6, l = t & 63;
    const int isO = blockIdx.x & 1;
    const float* __restrict__ src = isO ? fo : fa;
    float* part = isO ? partO : partA;

    const int pbase = (blockIdx.x >> 1) * 512;     // 512 px per block
    const int img   = pbase >> 14;
    const int hw0   = pbase & 16383;
    const float* g  = src + (size_t)img * BSTR + hw0;

    for (int i = t; i < 32 * 256; i += 256) accS[i] = 0.f;

    f32x4 acc0[16], acc1[16];
    #pragma unroll
    for (int n = 0; n < 16; ++n) {
        acc0[n] = (f32x4){0.f, 0.f, 0.f, 0.f};
        acc1[n] = (f32x4){0.f, 0.f, 0.f, 0.f};
    }

    const int lcol = l & 15;       // B col (ch within tile) / A row (cls)
    const int lk   = l >> 4;       // k-group: px = lk*8 + j

    for (int it = 0; it < 4; ++it) {
        const int off = w * 128 + it * 32 + lk * 8;   // local px offset

        // labels for THIS lane's 8 A-frag pixels (L2-hot small array)
        const int4 la = *(const int4*)&lab[pbase + off];
        const int4 lb = *(const int4*)&lab[pbase + off + 4];

        // stream 16 ch-tiles: loads are already in B-frag layout
        float s0 = 0.f, s1 = 0.f, s2 = 0.f, s3 = 0.f;
        float s4 = 0.f, s5 = 0.f, s6 = 0.f, s7 = 0.f;
        uint4 frag[16];
        #pragma unroll
        for (int n = 0; n < 16; ++n) {
            const float* p = g + (size_t)(n * 16 + lcol) * HW + off;
            float4 a = *(const float4*)p;
            float4 b = *(const float4*)(p + 4);
            s0 += a.x * a.x;  s1 += a.y * a.y;  s2 += a.z * a.z;  s3 += a.w * a.w;
            s4 += b.x * b.x;  s5 += b.y * b.y;  s6 += b.z * b.z;  s7 += b.w * b.w;
            frag[n].x = bfpack_trunc(a.x, a.y);
            frag[n].y = bfpack_trunc(a.z, a.w);
            frag[n].z = bfpack_trunc(b.x, b.y);
            frag[n].w = bfpack_trunc(b.z, b.w);
        }

        // ssq reduce across the 16 lanes sharing this px-group (lane bits 0-3)
        #pragma unroll
        for (int m = 1; m < 16; m <<= 1) {
            s0 += __shfl_xor(s0, m, 64);  s1 += __shfl_xor(s1, m, 64);
            s2 += __shfl_xor(s2, m, 64);  s3 += __shfl_xor(s3, m, 64);
            s4 += __shfl_xor(s4, m, 64);  s5 += __shfl_xor(s5, m, 64);
            s6 += __shfl_xor(s6, m, 64);  s7 += __shfl_xor(s7, m, 64);
        }
        const uint iv0 = f2bf(rsq_fast(fmaxf(s0, 1e-24f)));
        const uint iv1 = f2bf(rsq_fast(fmaxf(s1, 1e-24f)));
        const uint iv2 = f2bf(rsq_fast(fmaxf(s2, 1e-24f)));
        const uint iv3 = f2bf(rsq_fast(fmaxf(s3, 1e-24f)));
        const uint iv4 = f2bf(rsq_fast(fmaxf(s4, 1e-24f)));
        const uint iv5 = f2bf(rsq_fast(fmaxf(s5, 1e-24f)));
        const uint iv6 = f2bf(rsq_fast(fmaxf(s6, 1e-24f)));
        const uint iv7 = f2bf(rsq_fast(fmaxf(s7, 1e-24f)));

        // A-frags: onehot(label)*invn for cls rows lcol and 16+lcol
        const int cls0 = lcol, cls1 = 16 + lcol;
        uint4 u0, u1;
        u0.x = ohv(la.x, cls0, iv0) | (ohv(la.y, cls0, iv1) << 16);
        u0.y = ohv(la.z, cls0, iv2) | (ohv(la.w, cls0, iv3) << 16);
        u0.z = ohv(lb.x, cls0, iv4) | (ohv(lb.y, cls0, iv5) << 16);
        u0.w = ohv(lb.z, cls0, iv6) | (ohv(lb.w, cls0, iv7) << 16);
        u1.x = ohv(la.x, cls1, iv0) | (ohv(la.y, cls1, iv1) << 16);
        u1.y = ohv(la.z, cls1, iv2) | (ohv(la.w, cls1, iv3) << 16);
        u1.z = ohv(lb.x, cls1, iv4) | (ohv(lb.y, cls1, iv5) << 16);
        u1.w = ohv(lb.z, cls1, iv6) | (ohv(lb.w, cls1, iv7) << 16);
        const bf16x8 A0 = __builtin_bit_cast(bf16x8, u0);
        const bf16x8 A1 = __builtin_bit_cast(bf16x8, u1);

        #pragma unroll
        for (int n = 0; n < 16; ++n) {
            const bf16x8 B = __builtin_bit_cast(bf16x8, frag[n]);
            acc0[n] = __builtin_amdgcn_mfma_f32_16x16x32_bf16(A0, B, acc0[n], 0, 0, 0);
            acc1[n] = __builtin_amdgcn_mfma_f32_16x16x32_bf16(A1, B, acc1[n], 0, 0, 0);
        }
    }

    // --- epilogue: block LDS reduce (addresses distinct per wave), one flush ---
    __syncthreads();                       // accS zero + all waves done
    #pragma unroll
    for (int n = 0; n < 16; ++n) {
        const int col = n * 16 + lcol;
        #pragma unroll
        for (int r = 0; r < 4; ++r) {
            const int row = lk * 4 + r;    // D: col=lane&15, row=(lane>>4)*4+r
            unsafeAtomicAdd(&accS[row * 256 + col], acc0[n][r]);
            unsafeAtomicAdd(&accS[(16 + row) * 256 + col], acc1[n][r]);
        }
    }
    __syncthreads();
    const int rep = (blockIdx.x >> 1) & (NREP - 1);
    for (int i = t; i < KC; i += 256)
        unsafeAtomicAdd(&part[rep * KC + i], accS[i]);
}

// ---------------- kernel 3: finalize (tiny) ----------------
__global__ __launch_bounds__(256) void k_final(const float* __restrict__ partA,
                                               const float* __restrict__ partO,
                                               const float* __restrict__ cntPart,
                                               float* __restrict__ out)
{
    __shared__ float anc[NUMC * 260];
    __shared__ float con[NUMC * 260];
    __shared__ float adc[NUMC * 44];
    __shared__ float cntS[32];
    __shared__ float rowloss[NUMC];
    __shared__ float rowvalid[NUMC];

    if (threadIdx.x < 32) cntS[threadIdx.x] = 0.f;
    __syncthreads();
    for (int i = threadIdx.x; i < NLB * 32; i += 256)
        unsafeAtomicAdd(&cntS[i & 31], cntPart[i]);
    __syncthreads();

    for (int i = threadIdx.x; i < KC; i += 256) {
        float sA = 0.f, sO = 0.f;
        #pragma unroll
        for (int r = 0; r < NREP; ++r) { sA += partA[r * KC + i]; sO += partO[r * KC + i]; }
        int k = i >> 8, c = i & 255;
        float cn = cntS[k];
        bool pr = cn > 0.f;
        float d = pr ? cn : 1.f;
        anc[k * 260 + c] = pr ? sA / d : 0.f;
        con[k * 260 + c] = pr ? sO / d : 0.f;
    }
    __syncthreads();
    // adc[k][j] = dot(anc_k, contrast_j)/T,  contrast = [anc; con]
    for (int pair = threadIdx.x; pair < NUMC * 2 * NUMC; pair += 256) {
        int k = pair / (2 * NUMC);
        int j = pair % (2 * NUMC);
        const float* ar = anc + k * 260;
        const float* br = (j < NUMC) ? (anc + j * 260) : (con + (j - NUMC) * 260);
        float s = 0.f;
        for (int c = 0; c < CCH; c += 4) {
            float4 a4 = *(const float4*)(ar + c);
            float4 b4 = *(const float4*)(br + c);
            s += a4.x * b4.x + a4.y * b4.y + a4.z * b4.z + a4.w * b4.w;
        }
        adc[k * 44 + j] = s / 0.07f;
    }
    __syncthreads();
    if (threadIdx.x < NUMC) {
        int k = threadIdx.x;
        bool pr = cntS[k] > 0.f;
        float neg = 0.f;       // faithful to source — negatives use UNshifted logits
        float mx = -1e30f;
        for (int j = 0; j < 2 * NUMC; ++j) {
            int cj = (j < NUMC) ? j : (j - NUMC);
            bool cp = cntS[cj] > 0.f;
            float v = adc[k * 44 + j];
            if (cp) {
                if (v > mx) mx = v;
                if (j != k && j != NUMC + k) neg += expf(v);
            }
        }
        float sh = adc[k * 44 + NUMC + k] - mx;
        float rl = -(sh - logf(expf(sh) + neg));
        rowloss[k] = pr ? rl : 0.f;
        rowvalid[k] = pr ? 1.f : 0.f;
    }
    __syncthreads();
    if (threadIdx.x == 0) {
        float s = 0.f, v = 0.f;
        for (int kk = 0; kk < NUMC; ++kk) { s += rowloss[kk]; v += rowvalid[kk]; }
        out[0] = s / fmaxf(v, 1.f);
    }
}

// ---------------- launch ----------------
extern "C" void kernel_launch(void* const* d_in, const int* in_sizes, int n_in,
                              void* d_out, int out_size, void* d_ws, size_t ws_size,
                              hipStream_t stream) {
    const int*   labels      = (const int*)  d_in[0];
    const float* feats_old   = (const float*)d_in[1];
    const float* feats       = (const float*)d_in[2];
    const float* outputs_old = (const float*)d_in[3];
    // d_in[4] (outputs) and d_in[5] (prototypes) are unused by the reference math.

    float* ws      = (float*)d_ws;
    int*   lab     = (int*)ws;                     // [131072]
    float* partA   = ws + 131072;                  // [16*5376]
    float* partO   = partA + NREP * KC;            // [16*5376]
    float* cntPart = partO + NREP * KC;            // [512*32]

    // no memset: k_labels zeroes partA/partO and fully overwrites cntPart

    k_labels<<<NLB, 256, 0, stream>>>(labels, outputs_old, lab, cntPart, partA);
    k_msum  <<<512, 256, 0, stream>>>(feats, feats_old, lab, partA, partO);
    k_final <<<1, 256, 0, stream>>>(partA, partO, cntPart, (float*)d_out);
}

// Round 14
// 107.801 us; speedup vs baseline: 1.7545x; 1.7545x over previous
//
#include <hip/hip_runtime.h>
#include <math.h>

#define NPIX   131072      // 8*128*128
#define CCH    256
#define HW     16384       // 128*128
#define BSTR   4194304     // 256*16384 (features b-stride; == 16*262144 for outputs_old)
#define NUMC   21
#define KC     5376        // 21*256
#define NREP   16

typedef __attribute__((ext_vector_type(8))) short bf16x8;   // 8 bf16 (4 VGPRs)
typedef __attribute__((ext_vector_type(4))) float f32x4;

static __device__ __forceinline__ uint f2bf(float x) {      // f32 -> bf16 bits, RTNE
    uint u = __builtin_bit_cast(uint, x);
    return (u + 0x7FFFu + ((u >> 16) & 1u)) >> 16;
}
static __device__ __forceinline__ uint ohv(int lbl, int cls, uint iv) {
    return (lbl == cls) ? iv : 0u;                          // onehot*invn as bf16 bits
}
static __device__ __forceinline__ float rsq_fast(float x) { // single v_rsq_f32
#if __has_builtin(__builtin_amdgcn_rsqf)
    return __builtin_amdgcn_rsqf(x);
#else
    return rsqrtf(x);
#endif
}
// pack hi16(x),hi16(y) -> one word (bf16 trunc pair)
static __device__ __forceinline__ uint bfpack_trunc(float x, float y) {
    return __builtin_amdgcn_perm(__builtin_bit_cast(uint, y),
                                 __builtin_bit_cast(uint, x), 0x07060302u);
}

// ------ kernel 1: fused pseudo-labels + hw-contiguous stream + MFMA sums -----
// 1024 blocks (512 px-blocks x 2 tensors), R10's verified core. Labels computed
// in-block (LDS labS) while chunk-0 global loads are in flight; parity-0 blocks
// also emit per-block class counts. No separate k_labels dispatch, no lab[].
__global__ __launch_bounds__(256, 2) void k_fused(const int* __restrict__ labels,
                                                  const float* __restrict__ outputs_old,
                                                  const float* __restrict__ fa,
                                                  const float* __restrict__ fo,
                                                  float* __restrict__ partA,
                                                  float* __restrict__ partO,
                                                  float* __restrict__ cntPart)
{
    __shared__ ushort tileB[CCH * 128];   // 64 KB, row=ch (256B), XOR-swizzled
    __shared__ float  ssqP[4][128];       // per-wave ssq partials
    __shared__ float  invnS[128];
    __shared__ int    labS[256];
    __shared__ float  cnt[32];

    const int t = threadIdx.x;
    const int w = t >> 6, l = t & 63;
    const int isO = blockIdx.x & 1;
    const float* __restrict__ src = isO ? fo : fa;
    float* part = isO ? partO : partA;

    const int pbase = (blockIdx.x >> 1) * 256;
    const int img   = pbase >> 14;
    const int hw0   = pbase & 16383;
    const float* g  = src + (size_t)img * BSTR + hw0;

    f32x4 acc[2][4];
    #pragma unroll
    for (int m = 0; m < 2; ++m)
        #pragma unroll
        for (int n = 0; n < 4; ++n)
            acc[m][n] = (f32x4){0.f, 0.f, 0.f, 0.f};

    // contiguous wave-load: lanes 0-31 ch 2i+0, lanes 32-63 ch 2i+1,
    // each lane 4 consecutive px -> 2 x 512B segments per instruction.
#define LOADB(B, i0, c2) do { \
    _Pragma("unroll") \
    for (int i_ = 0; i_ < 8; ++i_) \
        B[i_] = *(const float4*)(g + (size_t)(w * 64 + 2 * ((i0) + i_) + (l >> 5)) * HW \
                                 + (c2) * 128 + (l & 31) * 4); \
    } while (0)

#define PROCB(B, i0) do { \
    _Pragma("unroll") \
    for (int i_ = 0; i_ < 8; ++i_) { \
        float4 v_ = B[i_]; \
        s4.x += v_.x * v_.x;  s4.y += v_.y * v_.y; \
        s4.z += v_.z * v_.z;  s4.w += v_.w * v_.w; \
        int ch_ = w * 64 + 2 * ((i0) + i_) + (l >> 5); \
        uint lo_ = bfpack_trunc(v_.x, v_.y); \
        uint hi_ = bfpack_trunc(v_.z, v_.w); \
        *(uint2*)((char*)tileB + ch_ * 256 + ((((l & 31) * 8)) ^ ((ch_ & 7) << 4))) = \
            make_uint2(lo_, hi_); \
    } \
    } while (0)

#define KSTEP(c2, ks) do { \
    float4 ivA_ = *(const float4*)&invnS[(ks) * 32 + (l >> 4) * 8]; \
    float4 ivB_ = *(const float4*)&invnS[(ks) * 32 + (l >> 4) * 8 + 4]; \
    uint iv0 = f2bf(ivA_.x), iv1 = f2bf(ivA_.y), iv2 = f2bf(ivA_.z), iv3 = f2bf(ivA_.w); \
    uint iv4 = f2bf(ivB_.x), iv5 = f2bf(ivB_.y), iv6 = f2bf(ivB_.z), iv7 = f2bf(ivB_.w); \
    int4 la_ = *(const int4*)&labS[(c2) * 128 + (ks) * 32 + (l >> 4) * 8]; \
    int4 lb_ = *(const int4*)&labS[(c2) * 128 + (ks) * 32 + (l >> 4) * 8 + 4]; \
    const int cls0_ = l & 15, cls1_ = 16 + (l & 15); \
    uint4 u0_, u1_; \
    u0_.x = ohv(la_.x, cls0_, iv0) | (ohv(la_.y, cls0_, iv1) << 16); \
    u0_.y = ohv(la_.z, cls0_, iv2) | (ohv(la_.w, cls0_, iv3) << 16); \
    u0_.z = ohv(lb_.x, cls0_, iv4) | (ohv(lb_.y, cls0_, iv5) << 16); \
    u0_.w = ohv(lb_.z, cls0_, iv6) | (ohv(lb_.w, cls0_, iv7) << 16); \
    u1_.x = ohv(la_.x, cls1_, iv0) | (ohv(la_.y, cls1_, iv1) << 16); \
    u1_.y = ohv(la_.z, cls1_, iv2) | (ohv(la_.w, cls1_, iv3) << 16); \
    u1_.z = ohv(lb_.x, cls1_, iv4) | (ohv(lb_.y, cls1_, iv5) << 16); \
    u1_.w = ohv(lb_.z, cls1_, iv6) | (ohv(lb_.w, cls1_, iv7) << 16); \
    bf16x8 A0_ = __builtin_bit_cast(bf16x8, u0_); \
    bf16x8 A1_ = __builtin_bit_cast(bf16x8, u1_); \
    _Pragma("unroll") \
    for (int n_ = 0; n_ < 4; ++n_) { \
        const int chrow_ = (w * 4 + n_) * 16 + (l & 15); \
        const bf16x8 B_ = *(const bf16x8*)((const char*)tileB + chrow_ * 256 \
                            + (((ks) * 64 + (l >> 4) * 16) ^ ((chrow_ & 7) << 4))); \
        acc[0][n_] = __builtin_amdgcn_mfma_f32_16x16x32_bf16(A0_, B_, acc[0][n_], 0, 0, 0); \
        acc[1][n_] = __builtin_amdgcn_mfma_f32_16x16x32_bf16(A1_, B_, acc[1][n_], 0, 0, 0); \
    } \
    } while (0)

    float4 bufA[8], bufB[8];
    float4 s4;

    // ---- prologue: chunk-0 first-half loads in flight ----
    LOADB(bufA, 0, 0);
    LOADB(bufB, 8, 0);

    // ---- pseudo-labels (overlaps the loads above) ----
    if (t < 32) cnt[t] = 0.f;
    __syncthreads();                       // cnt zero visible
    {
        const int p   = pbase + t;
        const int rem = p & 16383;
        const int hh  = rem >> 7;
        const int ww2 = rem & 127;
        int ld = labels[img * 262144 + hh * 4 * 512 + ww2 * 4];
        int out = ld;
        if (ld == 0) {
            const float* oo = outputs_old + (size_t)img * BSTR
                              + (size_t)(hh * 4) * 512 + ww2 * 4;
            float v0 = oo[0];
            float best = (v0 < 0.7f) ? 0.0f : v0;
            int bi = 0;
            #pragma unroll
            for (int c = 1; c < 16; ++c) {
                float v = oo[(size_t)c * 262144];
                v = (v < 0.7f) ? 0.0f : v;
                if (v > best) { best = v; bi = c; }   // strict > == first-occurrence
            }
            out = bi;
        }
        labS[t] = out;
        if (!isO) unsafeAtomicAdd(&cnt[out], 1.0f);
    }
    __syncthreads();                       // labS + cnt ready
    if (!isO && t < 32)
        cntPart[(blockIdx.x >> 1) * 32 + t] = (t < NUMC) ? cnt[t] : 0.f;

    // ---- chunk 0 ----
    s4 = (float4){0.f, 0.f, 0.f, 0.f};
    PROCB(bufA, 0);  LOADB(bufA, 16, 0);
    PROCB(bufB, 8);  LOADB(bufB, 24, 0);
    PROCB(bufA, 16); PROCB(bufB, 24);
    s4.x += __shfl_xor(s4.x, 32, 64);  s4.y += __shfl_xor(s4.y, 32, 64);
    s4.z += __shfl_xor(s4.z, 32, 64);  s4.w += __shfl_xor(s4.w, 32, 64);
    if (l < 32) *(float4*)&ssqP[w][l * 4] = s4;
    LOADB(bufA, 0, 1);                     // prefetch chunk-1 over reduce+MFMA
    LOADB(bufB, 8, 1);
    __syncthreads();                       // tile + ssqP ready
    if (t < 128)
        invnS[t] = rsq_fast(fmaxf(ssqP[0][t] + ssqP[1][t] + ssqP[2][t] + ssqP[3][t],
                                  1e-24f));
    __syncthreads();                       // invn ready
    KSTEP(0, 0); KSTEP(0, 1); KSTEP(0, 2); KSTEP(0, 3);
    __syncthreads();                       // tile free

    // ---- chunk 1 ----
    s4 = (float4){0.f, 0.f, 0.f, 0.f};
    PROCB(bufA, 0);  LOADB(bufA, 16, 1);
    PROCB(bufB, 8);  LOADB(bufB, 24, 1);
    PROCB(bufA, 16); PROCB(bufB, 24);
    s4.x += __shfl_xor(s4.x, 32, 64);  s4.y += __shfl_xor(s4.y, 32, 64);
    s4.z += __shfl_xor(s4.z, 32, 64);  s4.w += __shfl_xor(s4.w, 32, 64);
    if (l < 32) *(float4*)&ssqP[w][l * 4] = s4;
    __syncthreads();
    if (t < 128)
        invnS[t] = rsq_fast(fmaxf(ssqP[0][t] + ssqP[1][t] + ssqP[2][t] + ssqP[3][t],
                                  1e-24f));
    __syncthreads();
    KSTEP(1, 0); KSTEP(1, 1); KSTEP(1, 2); KSTEP(1, 3);

#undef LOADB
#undef PROCB
#undef KSTEP

    // --- epilogue: D[cls][ch] -> replica atomics (col=lane&15, row=(lane>>4)*4+r) ---
    const int rep = (blockIdx.x >> 1) & (NREP - 1);
    #pragma unroll
    for (int m = 0; m < 2; ++m)
        #pragma unroll
        for (int n = 0; n < 4; ++n) {
            const int col = (w * 4 + n) * 16 + (l & 15);
            #pragma unroll
            for (int r = 0; r < 4; ++r) {
                const int row = m * 16 + (l >> 4) * 4 + r;
                if (row < NUMC)
                    unsafeAtomicAdd(&part[rep * KC + row * 256 + col], acc[m][n][r]);
            }
        }
}

// -------- kernel 2: parallel rep-reduction (42 rows) + count reduction --------
__global__ __launch_bounds__(256) void k_red(const float* __restrict__ partA,
                                             const float* __restrict__ partO,
                                             const float* __restrict__ cntPart,
                                             float* __restrict__ gsum,
                                             float* __restrict__ gcnt)
{
    const int b = blockIdx.x, t = threadIdx.x;
    if (b < 42) {
        const float* part = (b < 21) ? partA : partO;
        const int cls = (b < 21) ? b : b - 21;
        float s = 0.f;
        #pragma unroll
        for (int r = 0; r < NREP; ++r) s += part[r * KC + cls * 256 + t];
        gsum[b * 256 + t] = s;
    } else {
        __shared__ float cs[32];
        if (t < 32) cs[t] = 0.f;
        __syncthreads();
        float s = 0.f;
        for (int i = t; i < 512 * 32; i += 256) s += cntPart[i];  // i&31 fixed per thread
        unsafeAtomicAdd(&cs[t & 31], s);                          // 8-way, cheap
        __syncthreads();
        if (t < NUMC) gcnt[t] = cs[t];
    }
}

// ---------------- kernel 3: finalize (tiny, 43 KB in) ----------------
__global__ __launch_bounds__(256) void k_final2(const float* __restrict__ gsum,
                                                const float* __restrict__ gcnt,
                                                float* __restrict__ out)
{
    __shared__ float anc[NUMC * 260];
    __shared__ float con[NUMC * 260];
    __shared__ float adc[NUMC * 44];
    __shared__ float cntS[NUMC];
    __shared__ float rowloss[NUMC];
    __shared__ float rowvalid[NUMC];

    if (threadIdx.x < NUMC) cntS[threadIdx.x] = gcnt[threadIdx.x];
    __syncthreads();
    for (int i = threadIdx.x; i < KC; i += 256) {
        int k = i >> 8, c = i & 255;
        float cn = cntS[k];
        bool pr = cn > 0.f;
        float d = pr ? cn : 1.f;
        anc[k * 260 + c] = pr ? gsum[k * 256 + c] / d : 0.f;
        con[k * 260 + c] = pr ? gsum[(NUMC + k) * 256 + c] / d : 0.f;
    }
    __syncthreads();
    // adc[k][j] = dot(anc_k, contrast_j)/T,  contrast = [anc; con]
    for (int pair = threadIdx.x; pair < NUMC * 2 * NUMC; pair += 256) {
        int k = pair / (2 * NUMC);
        int j = pair % (2 * NUMC);
        const float* ar = anc + k * 260;
        const float* br = (j < NUMC) ? (anc + j * 260) : (con + (j - NUMC) * 260);
        float s = 0.f;
        for (int c = 0; c < CCH; c += 4) {
            float4 a4 = *(const float4*)(ar + c);
            float4 b4 = *(const float4*)(br + c);
            s += a4.x * b4.x + a4.y * b4.y + a4.z * b4.z + a4.w * b4.w;
        }
        adc[k * 44 + j] = s / 0.07f;
    }
    __syncthreads();
    if (threadIdx.x < NUMC) {
        int k = threadIdx.x;
        bool pr = cntS[k] > 0.f;
        float neg = 0.f;       // faithful to source — negatives use UNshifted logits
        float mx = -1e30f;
        for (int j = 0; j < 2 * NUMC; ++j) {
            int cj = (j < NUMC) ? j : (j - NUMC);
            bool cp = cntS[cj] > 0.f;
            float v = adc[k * 44 + j];
            if (cp) {
                if (v > mx) mx = v;
                if (j != k && j != NUMC + k) neg += expf(v);
            }
        }
        float sh = adc[k * 44 + NUMC + k] - mx;
        float rl = -(sh - logf(expf(sh) + neg));
        rowloss[k] = pr ? rl : 0.f;
        rowvalid[k] = pr ? 1.f : 0.f;
    }
    __syncthreads();
    if (threadIdx.x == 0) {
        float s = 0.f, v = 0.f;
        for (int kk = 0; kk < NUMC; ++kk) { s += rowloss[kk]; v += rowvalid[kk]; }
        out[0] = s / fmaxf(v, 1.f);
    }
}

// ---------------- launch ----------------
extern "C" void kernel_launch(void* const* d_in, const int* in_sizes, int n_in,
                              void* d_out, int out_size, void* d_ws, size_t ws_size,
                              hipStream_t stream) {
    const int*   labels      = (const int*)  d_in[0];
    const float* feats_old   = (const float*)d_in[1];
    const float* feats       = (const float*)d_in[2];
    const float* outputs_old = (const float*)d_in[3];
    // d_in[4] (outputs) and d_in[5] (prototypes) are unused by the reference math.

    float* ws      = (float*)d_ws;
    float* partA   = ws;                           // [16*5376]
    float* partO   = partA + NREP * KC;            // [16*5376]
    float* cntPart = partO + NREP * KC;            // [512*32]
    float* gsum    = cntPart + 512 * 32;           // [42*256]
    float* gcnt    = gsum + 42 * 256;              // [21]

    hipMemsetAsync(partA, 0, (size_t)(2 * NREP * KC) * sizeof(float), stream);

    k_fused <<<1024, 256, 0, stream>>>(labels, outputs_old, feats, feats_old,
                                       partA, partO, cntPart);
    k_red   <<<43, 256, 0, stream>>>(partA, partO, cntPart, gsum, gcnt);
    k_final2<<<1, 256, 0, stream>>>(gsum, gcnt, (float*)d_out);
}

// Round 15
// 105.338 us; speedup vs baseline: 1.7955x; 1.0234x over previous
//
#include <hip/hip_runtime.h>
#include <math.h>

#define NPIX   131072      // 8*128*128
#define CCH    256
#define HW     16384       // 128*128
#define BSTR   4194304     // 256*16384 (features b-stride)
#define NUMC   21
#define KC     5376        // 21*256
#define NREP   16
#define NLB    512         // k_labels blocks

typedef __attribute__((ext_vector_type(8))) short bf16x8;   // 8 bf16 (4 VGPRs)
typedef __attribute__((ext_vector_type(4))) float f32x4;

static __device__ __forceinline__ uint f2bf(float x) {      // f32 -> bf16 bits, RTNE
    uint u = __builtin_bit_cast(uint, x);
    return (u + 0x7FFFu + ((u >> 16) & 1u)) >> 16;
}
static __device__ __forceinline__ uint ohv(int lbl, int cls, uint iv) {
    return (lbl == cls) ? iv : 0u;                          // onehot*invn as bf16 bits
}
static __device__ __forceinline__ float rsq_fast(float x) { // single v_rsq_f32
#if __has_builtin(__builtin_amdgcn_rsqf)
    return __builtin_amdgcn_rsqf(x);
#else
    return rsqrtf(x);
#endif
}
// pack hi16(x),hi16(y) -> one word (bf16 trunc pair)
static __device__ __forceinline__ uint bfpack_trunc(float x, float y) {
    return __builtin_amdgcn_perm(__builtin_bit_cast(uint, y),
                                 __builtin_bit_cast(uint, x), 0x07060302u);
}

// ------- kernel 1: pseudo labels + per-block counts + zero part buffers -------
__global__ __launch_bounds__(256) void k_labels(const int* __restrict__ labels,
                                                const float* __restrict__ outputs_old,
                                                int* __restrict__ lab,
                                                float* __restrict__ cntPart,
                                                float* __restrict__ partzero)
{
    __shared__ float cnt[NUMC];
    if (threadIdx.x < NUMC) cnt[threadIdx.x] = 0.f;
    __syncthreads();

    // zero this block's slice of partA/partO (172032 floats / 512 blocks = 336)
    {
        float* pz = partzero + blockIdx.x * 336;
        for (int i = threadIdx.x; i < 336; i += 256) pz[i] = 0.f;
    }

    int p = blockIdx.x * 256 + threadIdx.x;
    int b = p >> 14;
    int rem = p & 16383;
    int h = rem >> 7;
    int w = rem & 127;
    int ld = labels[b * 262144 + (h * 4) * 512 + (w * 4)];
    int out = ld;
    if (ld == 0) {
        const float* oo = outputs_old + (size_t)b * BSTR + (size_t)(h * 4) * 512 + (w * 4);
        float v0 = oo[0];
        float best = (v0 < 0.7f) ? 0.0f : v0;
        int bi = 0;
        #pragma unroll
        for (int c = 1; c < 16; ++c) {
            float v = oo[(size_t)c * 262144];
            v = (v < 0.7f) ? 0.0f : v;
            if (v > best) { best = v; bi = c; }   // strict > == first-occurrence argmax
        }
        out = bi;
    }
    lab[p] = out;
    unsafeAtomicAdd(&cnt[out], 1.0f);
    __syncthreads();
    if (threadIdx.x < 32)
        cntPart[blockIdx.x * 32 + threadIdx.x] =
            (threadIdx.x < NUMC) ? cnt[threadIdx.x] : 0.f;   // full overwrite, no pre-zero
}

// ---------------- kernel 2: hw-contiguous stream + MFMA per-class sums -------
// VERBATIM R10 core (best measured: 96.5 us clean total).
// Block = 256 px of one tensor (2 chunks x 128 px), 4 waves. Contiguous loads
// (2x512B segments/instr); ssq lane-local; bf16 tile [256ch][128px] XOR-swizzled.
__global__ __launch_bounds__(256, 2) void k_msum(const float* __restrict__ fa,
                                                 const float* __restrict__ fo,
                                                 const int* __restrict__ lab,
                                                 float* __restrict__ partA,
                                                 float* __restrict__ partO)
{
    __shared__ ushort tileB[CCH * 128];   // 64 KB, row=ch (256B), XOR-swizzled
    __shared__ float  ssqP[4][128];       // per-wave ssq partials
    __shared__ float  invnS[128];
    __shared__ int    labS[256];

    const int t = threadIdx.x;
    const int w = t >> 6, l = t & 63;
    const int isO = blockIdx.x & 1;
    const float* __restrict__ src = isO ? fo : fa;
    float* part = isO ? partO : partA;

    const int pbase = (blockIdx.x >> 1) * 256;
    const int img   = pbase >> 14;
    const int hw0   = pbase & 16383;
    const float* g  = src + (size_t)img * BSTR + hw0;

    labS[t] = lab[pbase + t];

    f32x4 acc[2][4];
    #pragma unroll
    for (int m = 0; m < 2; ++m)
        #pragma unroll
        for (int n = 0; n < 4; ++n)
            acc[m][n] = (f32x4){0.f, 0.f, 0.f, 0.f};

#define LOADB(B, i0) do { \
    _Pragma("unroll") \
    for (int i_ = 0; i_ < 8; ++i_) \
        B[i_] = *(const float4*)(gc + (size_t)(w * 64 + 2 * ((i0) + i_) + (l >> 5)) * HW \
                                 + (l & 31) * 4); \
    } while (0)

#define PROCB(B, i0) do { \
    _Pragma("unroll") \
    for (int i_ = 0; i_ < 8; ++i_) { \
        float4 v_ = B[i_]; \
        s4.x += v_.x * v_.x;  s4.y += v_.y * v_.y; \
        s4.z += v_.z * v_.z;  s4.w += v_.w * v_.w; \
        int ch_ = w * 64 + 2 * ((i0) + i_) + (l >> 5); \
        uint lo_ = bfpack_trunc(v_.x, v_.y); \
        uint hi_ = bfpack_trunc(v_.z, v_.w); \
        *(uint2*)((char*)tileB + ch_ * 256 + ((((l & 31) * 8)) ^ ((ch_ & 7) << 4))) = \
            make_uint2(lo_, hi_); \
    } \
    } while (0)

#define KSTEP(c2, ks) do { \
    float4 ivA_ = *(const float4*)&invnS[(ks) * 32 + (l >> 4) * 8]; \
    float4 ivB_ = *(const float4*)&invnS[(ks) * 32 + (l >> 4) * 8 + 4]; \
    uint iv0 = f2bf(ivA_.x), iv1 = f2bf(ivA_.y), iv2 = f2bf(ivA_.z), iv3 = f2bf(ivA_.w); \
    uint iv4 = f2bf(ivB_.x), iv5 = f2bf(ivB_.y), iv6 = f2bf(ivB_.z), iv7 = f2bf(ivB_.w); \
    int4 la_ = *(const int4*)&labS[(c2) * 128 + (ks) * 32 + (l >> 4) * 8]; \
    int4 lb_ = *(const int4*)&labS[(c2) * 128 + (ks) * 32 + (l >> 4) * 8 + 4]; \
    const int cls0_ = l & 15, cls1_ = 16 + (l & 15); \
    uint4 u0_, u1_; \
    u0_.x = ohv(la_.x, cls0_, iv0) | (ohv(la_.y, cls0_, iv1) << 16); \
    u0_.y = ohv(la_.z, cls0_, iv2) | (ohv(la_.w, cls0_, iv3) << 16); \
    u0_.z = ohv(lb_.x, cls0_, iv4) | (ohv(lb_.y, cls0_, iv5) << 16); \
    u0_.w = ohv(lb_.z, cls0_, iv6) | (ohv(lb_.w, cls0_, iv7) << 16); \
    u1_.x = ohv(la_.x, cls1_, iv0) | (ohv(la_.y, cls1_, iv1) << 16); \
    u1_.y = ohv(la_.z, cls1_, iv2) | (ohv(la_.w, cls1_, iv3) << 16); \
    u1_.z = ohv(lb_.x, cls1_, iv4) | (ohv(lb_.y, cls1_, iv5) << 16); \
    u1_.w = ohv(lb_.z, cls1_, iv6) | (ohv(lb_.w, cls1_, iv7) << 16); \
    bf16x8 A0_ = __builtin_bit_cast(bf16x8, u0_); \
    bf16x8 A1_ = __builtin_bit_cast(bf16x8, u1_); \
    _Pragma("unroll") \
    for (int n_ = 0; n_ < 4; ++n_) { \
        const int chrow_ = (w * 4 + n_) * 16 + (l & 15); \
        const bf16x8 B_ = *(const bf16x8*)((const char*)tileB + chrow_ * 256 \
                            + (((ks) * 64 + (l >> 4) * 16) ^ ((chrow_ & 7) << 4))); \
        acc[0][n_] = __builtin_amdgcn_mfma_f32_16x16x32_bf16(A0_, B_, acc[0][n_], 0, 0, 0); \
        acc[1][n_] = __builtin_amdgcn_mfma_f32_16x16x32_bf16(A1_, B_, acc[1][n_], 0, 0, 0); \
    } \
    } while (0)

#define CHUNK(c2, LAST) do { \
    const float* gc = g + (c2) * 128; \
    float4 s4 = {0.f, 0.f, 0.f, 0.f}; \
    float4 bufA[8], bufB[8]; \
    LOADB(bufA, 0);  LOADB(bufB, 8); \
    PROCB(bufA, 0);  LOADB(bufA, 16); \
    PROCB(bufB, 8);  LOADB(bufB, 24); \
    PROCB(bufA, 16); PROCB(bufB, 24); \
    s4.x += __shfl_xor(s4.x, 32, 64);  s4.y += __shfl_xor(s4.y, 32, 64); \
    s4.z += __shfl_xor(s4.z, 32, 64);  s4.w += __shfl_xor(s4.w, 32, 64); \
    if (l < 32) *(float4*)&ssqP[w][l * 4] = s4; \
    __syncthreads(); \
    if (t < 128) { \
        float ss_ = ssqP[0][t] + ssqP[1][t] + ssqP[2][t] + ssqP[3][t]; \
        invnS[t] = rsq_fast(fmaxf(ss_, 1e-24f)); \
    } \
    __syncthreads(); \
    KSTEP(c2, 0); KSTEP(c2, 1); KSTEP(c2, 2); KSTEP(c2, 3); \
    if (!(LAST)) __syncthreads(); \
    } while (0)

    CHUNK(0, 0);
    CHUNK(1, 1);

#undef LOADB
#undef PROCB
#undef KSTEP
#undef CHUNK

    // --- epilogue: D[cls][ch] -> replica atomics (col=lane&15, row=(lane>>4)*4+r) ---
    const int rep = (blockIdx.x >> 1) & (NREP - 1);
    #pragma unroll
    for (int m = 0; m < 2; ++m)
        #pragma unroll
        for (int n = 0; n < 4; ++n) {
            const int col = (w * 4 + n) * 16 + (l & 15);
            #pragma unroll
            for (int r = 0; r < 4; ++r) {
                const int row = m * 16 + (l >> 4) * 4 + r;
                if (row < NUMC)
                    unsafeAtomicAdd(&part[rep * KC + row * 256 + col], acc[m][n][r]);
            }
        }
}

// -------- kernel 3: parallel rep-reduction (42 rows) + count reduction --------
__global__ __launch_bounds__(256) void k_red(const float* __restrict__ partA,
                                             const float* __restrict__ partO,
                                             const float* __restrict__ cntPart,
                                             float* __restrict__ gsum,
                                             float* __restrict__ gcnt)
{
    const int b = blockIdx.x, t = threadIdx.x;
    if (b < 42) {
        const float* part = (b < 21) ? partA : partO;
        const int cls = (b < 21) ? b : b - 21;
        float s = 0.f;
        #pragma unroll
        for (int r = 0; r < NREP; ++r) s += part[r * KC + cls * 256 + t];
        gsum[b * 256 + t] = s;
    } else {
        __shared__ float cs[32];
        if (t < 32) cs[t] = 0.f;
        __syncthreads();
        float s = 0.f;
        for (int i = t; i < NLB * 32; i += 256) s += cntPart[i];  // i&31 fixed per thread
        unsafeAtomicAdd(&cs[t & 31], s);                          // 8-way, cheap
        __syncthreads();
        if (t < NUMC) gcnt[t] = cs[t];
    }
}

// ---------------- kernel 4: finalize (tiny, 43 KB in) ----------------
__global__ __launch_bounds__(256) void k_final2(const float* __restrict__ gsum,
                                                const float* __restrict__ gcnt,
                                                float* __restrict__ out)
{
    __shared__ float anc[NUMC * 260];
    __shared__ float con[NUMC * 260];
    __shared__ float adc[NUMC * 44];
    __shared__ float cntS[NUMC];
    __shared__ float rowloss[NUMC];
    __shared__ float rowvalid[NUMC];

    if (threadIdx.x < NUMC) cntS[threadIdx.x] = gcnt[threadIdx.x];
    __syncthreads();
    for (int i = threadIdx.x; i < KC; i += 256) {
        int k = i >> 8, c = i & 255;
        float cn = cntS[k];
        bool pr = cn > 0.f;
        float d = pr ? cn : 1.f;
        anc[k * 260 + c] = pr ? gsum[k * 256 + c] / d : 0.f;
        con[k * 260 + c] = pr ? gsum[(NUMC + k) * 256 + c] / d : 0.f;
    }
    __syncthreads();
    // adc[k][j] = dot(anc_k, contrast_j)/T,  contrast = [anc; con]
    for (int pair = threadIdx.x; pair < NUMC * 2 * NUMC; pair += 256) {
        int k = pair / (2 * NUMC);
        int j = pair % (2 * NUMC);
        const float* ar = anc + k * 260;
        const float* br = (j < NUMC) ? (anc + j * 260) : (con + (j - NUMC) * 260);
        float s = 0.f;
        for (int c = 0; c < CCH; c += 4) {
            float4 a4 = *(const float4*)(ar + c);
            float4 b4 = *(const float4*)(br + c);
            s += a4.x * b4.x + a4.y * b4.y + a4.z * b4.z + a4.w * b4.w;
        }
        adc[k * 44 + j] = s / 0.07f;
    }
    __syncthreads();
    if (threadIdx.x < NUMC) {
        int k = threadIdx.x;
        bool pr = cntS[k] > 0.f;
        float neg = 0.f;       // faithful to source — negatives use UNshifted logits
        float mx = -1e30f;
        for (int j = 0; j < 2 * NUMC; ++j) {
            int cj = (j < NUMC) ? j : (j - NUMC);
            bool cp = cntS[cj] > 0.f;
            float v = adc[k * 44 + j];
            if (cp) {
                if (v > mx) mx = v;
                if (j != k && j != NUMC + k) neg += expf(v);
            }
        }
        float sh = adc[k * 44 + NUMC + k] - mx;
        float rl = -(sh - logf(expf(sh) + neg));
        rowloss[k] = pr ? rl : 0.f;
        rowvalid[k] = pr ? 1.f : 0.f;
    }
    __syncthreads();
    if (threadIdx.x == 0) {
        float s = 0.f, v = 0.f;
        for (int kk = 0; kk < NUMC; ++kk) { s += rowloss[kk]; v += rowvalid[kk]; }
        out[0] = s / fmaxf(v, 1.f);
    }
}

// ---------------- launch ----------------
extern "C" void kernel_launch(void* const* d_in, const int* in_sizes, int n_in,
                              void* d_out, int out_size, void* d_ws, size_t ws_size,
                              hipStream_t stream) {
    const int*   labels      = (const int*)  d_in[0];
    const float* feats_old   = (const float*)d_in[1];
    const float* feats       = (const float*)d_in[2];
    const float* outputs_old = (const float*)d_in[3];
    // d_in[4] (outputs) and d_in[5] (prototypes) are unused by the reference math.

    float* ws      = (float*)d_ws;
    int*   lab     = (int*)ws;                     // [131072]
    float* partA   = ws + 131072;                  // [16*5376]
    float* partO   = partA + NREP * KC;            // [16*5376]
    float* cntPart = partO + NREP * KC;            // [512*32]
    float* gsum    = cntPart + NLB * 32;           // [42*256]
    float* gcnt    = gsum + 42 * 256;              // [21]

    // no memset: k_labels zeroes partA/partO and fully overwrites cntPart

    k_labels<<<NLB, 256, 0, stream>>>(labels, outputs_old, lab, cntPart, partA);
    k_msum  <<<1024, 256, 0, stream>>>(feats, feats_old, lab, partA, partO);
    k_red   <<<43, 256, 0, stream>>>(partA, partO, cntPart, gsum, gcnt);
    k_final2<<<1, 256, 0, stream>>>(gsum, gcnt, (float*)d_out);
}

// Round 16
// 101.220 us; speedup vs baseline: 1.8686x; 1.0407x over previous
//
#include <hip/hip_runtime.h>
#include <math.h>

#define NPIX   131072      // 8*128*128
#define CCH    256
#define HW     16384       // 128*128
#define BSTR   4194304     // 256*16384 (features b-stride)
#define NUMC   21
#define KC     5376        // 21*256
#define NREP   16

typedef __attribute__((ext_vector_type(8))) short bf16x8;   // 8 bf16 (4 VGPRs)
typedef __attribute__((ext_vector_type(4))) float f32x4;

static __device__ __forceinline__ uint f2bf(float x) {      // f32 -> bf16 bits, RTNE
    uint u = __builtin_bit_cast(uint, x);
    return (u + 0x7FFFu + ((u >> 16) & 1u)) >> 16;
}
static __device__ __forceinline__ uint ohv(int lbl, int cls, uint iv) {
    return (lbl == cls) ? iv : 0u;                          // onehot*invn as bf16 bits
}
static __device__ __forceinline__ float rsq_fast(float x) { // single v_rsq_f32
#if __has_builtin(__builtin_amdgcn_rsqf)
    return __builtin_amdgcn_rsqf(x);
#else
    return rsqrtf(x);
#endif
}
// pack hi16(x),hi16(y) -> one word (bf16 trunc pair)
static __device__ __forceinline__ uint bfpack_trunc(float x, float y) {
    return __builtin_amdgcn_perm(__builtin_bit_cast(uint, y),
                                 __builtin_bit_cast(uint, x), 0x07060302u);
}

// ---------------- kernel 1: pseudo labels + per-class counts ----------------
// VERBATIM R10 (part of the 96.5 us champion config).
__global__ __launch_bounds__(256) void k_labels(const int* __restrict__ labels,
                                                const float* __restrict__ outputs_old,
                                                int* __restrict__ lab,
                                                float* __restrict__ gcnt)
{
    __shared__ float cnt[NUMC];
    if (threadIdx.x < NUMC) cnt[threadIdx.x] = 0.f;
    __syncthreads();

    int p = blockIdx.x * 256 + threadIdx.x;
    int b = p >> 14;
    int rem = p & 16383;
    int h = rem >> 7;
    int w = rem & 127;
    int ld = labels[b * 262144 + (h * 4) * 512 + (w * 4)];
    int out = ld;
    if (ld == 0) {
        const float* oo = outputs_old + (size_t)b * BSTR + (size_t)(h * 4) * 512 + (w * 4);
        float v0 = oo[0];
        float best = (v0 < 0.7f) ? 0.0f : v0;
        int bi = 0;
        #pragma unroll
        for (int c = 1; c < 16; ++c) {
            float v = oo[(size_t)c * 262144];
            v = (v < 0.7f) ? 0.0f : v;
            if (v > best) { best = v; bi = c; }   // strict > == first-occurrence argmax
        }
        out = bi;
    }
    lab[p] = out;
    unsafeAtomicAdd(&cnt[out], 1.0f);
    __syncthreads();
    if (threadIdx.x < NUMC) unsafeAtomicAdd(&gcnt[threadIdx.x], cnt[threadIdx.x]);
}

// ---------------- kernel 2: hw-contiguous stream + MFMA per-class sums -------
// VERBATIM R10 core (best measured: 96.5 us clean total).
__global__ __launch_bounds__(256, 2) void k_msum(const float* __restrict__ fa,
                                                 const float* __restrict__ fo,
                                                 const int* __restrict__ lab,
                                                 float* __restrict__ partA,
                                                 float* __restrict__ partO)
{
    __shared__ ushort tileB[CCH * 128];   // 64 KB, row=ch (256B), XOR-swizzled
    __shared__ float  ssqP[4][128];       // per-wave ssq partials
    __shared__ float  invnS[128];
    __shared__ int    labS[256];

    const int t = threadIdx.x;
    const int w = t >> 6, l = t & 63;
    const int isO = blockIdx.x & 1;
    const float* __restrict__ src = isO ? fo : fa;
    float* part = isO ? partO : partA;

    const int pbase = (blockIdx.x >> 1) * 256;
    const int img   = pbase >> 14;
    const int hw0   = pbase & 16383;
    const float* g  = src + (size_t)img * BSTR + hw0;

    labS[t] = lab[pbase + t];

    f32x4 acc[2][4];
    #pragma unroll
    for (int m = 0; m < 2; ++m)
        #pragma unroll
        for (int n = 0; n < 4; ++n)
            acc[m][n] = (f32x4){0.f, 0.f, 0.f, 0.f};

#define LOADB(B, i0) do { \
    _Pragma("unroll") \
    for (int i_ = 0; i_ < 8; ++i_) \
        B[i_] = *(const float4*)(gc + (size_t)(w * 64 + 2 * ((i0) + i_) + (l >> 5)) * HW \
                                 + (l & 31) * 4); \
    } while (0)

#define PROCB(B, i0) do { \
    _Pragma("unroll") \
    for (int i_ = 0; i_ < 8; ++i_) { \
        float4 v_ = B[i_]; \
        s4.x += v_.x * v_.x;  s4.y += v_.y * v_.y; \
        s4.z += v_.z * v_.z;  s4.w += v_.w * v_.w; \
        int ch_ = w * 64 + 2 * ((i0) + i_) + (l >> 5); \
        uint lo_ = bfpack_trunc(v_.x, v_.y); \
        uint hi_ = bfpack_trunc(v_.z, v_.w); \
        *(uint2*)((char*)tileB + ch_ * 256 + ((((l & 31) * 8)) ^ ((ch_ & 7) << 4))) = \
            make_uint2(lo_, hi_); \
    } \
    } while (0)

#define KSTEP(c2, ks) do { \
    float4 ivA_ = *(const float4*)&invnS[(ks) * 32 + (l >> 4) * 8]; \
    float4 ivB_ = *(const float4*)&invnS[(ks) * 32 + (l >> 4) * 8 + 4]; \
    uint iv0 = f2bf(ivA_.x), iv1 = f2bf(ivA_.y), iv2 = f2bf(ivA_.z), iv3 = f2bf(ivA_.w); \
    uint iv4 = f2bf(ivB_.x), iv5 = f2bf(ivB_.y), iv6 = f2bf(ivB_.z), iv7 = f2bf(ivB_.w); \
    int4 la_ = *(const int4*)&labS[(c2) * 128 + (ks) * 32 + (l >> 4) * 8]; \
    int4 lb_ = *(const int4*)&labS[(c2) * 128 + (ks) * 32 + (l >> 4) * 8 + 4]; \
    const int cls0_ = l & 15, cls1_ = 16 + (l & 15); \
    uint4 u0_, u1_; \
    u0_.x = ohv(la_.x, cls0_, iv0) | (ohv(la_.y, cls0_, iv1) << 16); \
    u0_.y = ohv(la_.z, cls0_, iv2) | (ohv(la_.w, cls0_, iv3) << 16); \
    u0_.z = ohv(lb_.x, cls0_, iv4) | (ohv(lb_.y, cls0_, iv5) << 16); \
    u0_.w = ohv(lb_.z, cls0_, iv6) | (ohv(lb_.w, cls0_, iv7) << 16); \
    u1_.x = ohv(la_.x, cls1_, iv0) | (ohv(la_.y, cls1_, iv1) << 16); \
    u1_.y = ohv(la_.z, cls1_, iv2) | (ohv(la_.w, cls1_, iv3) << 16); \
    u1_.z = ohv(lb_.x, cls1_, iv4) | (ohv(lb_.y, cls1_, iv5) << 16); \
    u1_.w = ohv(lb_.z, cls1_, iv6) | (ohv(lb_.w, cls1_, iv7) << 16); \
    bf16x8 A0_ = __builtin_bit_cast(bf16x8, u0_); \
    bf16x8 A1_ = __builtin_bit_cast(bf16x8, u1_); \
    _Pragma("unroll") \
    for (int n_ = 0; n_ < 4; ++n_) { \
        const int chrow_ = (w * 4 + n_) * 16 + (l & 15); \
        const bf16x8 B_ = *(const bf16x8*)((const char*)tileB + chrow_ * 256 \
                            + (((ks) * 64 + (l >> 4) * 16) ^ ((chrow_ & 7) << 4))); \
        acc[0][n_] = __builtin_amdgcn_mfma_f32_16x16x32_bf16(A0_, B_, acc[0][n_], 0, 0, 0); \
        acc[1][n_] = __builtin_amdgcn_mfma_f32_16x16x32_bf16(A1_, B_, acc[1][n_], 0, 0, 0); \
    } \
    } while (0)

#define CHUNK(c2, LAST) do { \
    const float* gc = g + (c2) * 128; \
    float4 s4 = {0.f, 0.f, 0.f, 0.f}; \
    float4 bufA[8], bufB[8]; \
    LOADB(bufA, 0);  LOADB(bufB, 8); \
    PROCB(bufA, 0);  LOADB(bufA, 16); \
    PROCB(bufB, 8);  LOADB(bufB, 24); \
    PROCB(bufA, 16); PROCB(bufB, 24); \
    s4.x += __shfl_xor(s4.x, 32, 64);  s4.y += __shfl_xor(s4.y, 32, 64); \
    s4.z += __shfl_xor(s4.z, 32, 64);  s4.w += __shfl_xor(s4.w, 32, 64); \
    if (l < 32) *(float4*)&ssqP[w][l * 4] = s4; \
    __syncthreads(); \
    if (t < 128) { \
        float ss_ = ssqP[0][t] + ssqP[1][t] + ssqP[2][t] + ssqP[3][t]; \
        invnS[t] = rsq_fast(fmaxf(ss_, 1e-24f)); \
    } \
    __syncthreads(); \
    KSTEP(c2, 0); KSTEP(c2, 1); KSTEP(c2, 2); KSTEP(c2, 3); \
    if (!(LAST)) __syncthreads(); \
    } while (0)

    CHUNK(0, 0);
    CHUNK(1, 1);

#undef LOADB
#undef PROCB
#undef KSTEP
#undef CHUNK

    // --- epilogue: D[cls][ch] -> replica atomics (col=lane&15, row=(lane>>4)*4+r) ---
    const int rep = (blockIdx.x >> 1) & (NREP - 1);
    #pragma unroll
    for (int m = 0; m < 2; ++m)
        #pragma unroll
        for (int n = 0; n < 4; ++n) {
            const int col = (w * 4 + n) * 16 + (l & 15);
            #pragma unroll
            for (int r = 0; r < 4; ++r) {
                const int row = m * 16 + (l >> 4) * 4 + r;
                if (row < NUMC)
                    unsafeAtomicAdd(&part[rep * KC + row * 256 + col], acc[m][n][r]);
            }
        }
}

// -------- kernel 3: parallel rep-reduction (42 rows, 688 KB in parallel) -----
__global__ __launch_bounds__(256) void k_red(const float* __restrict__ partA,
                                             const float* __restrict__ partO,
                                             float* __restrict__ gsum)
{
    const int b = blockIdx.x, t = threadIdx.x;
    const float* part = (b < 21) ? partA : partO;
    const int cls = (b < 21) ? b : b - 21;
    float s = 0.f;
    #pragma unroll
    for (int r = 0; r < NREP; ++r) s += part[r * KC + cls * 256 + t];
    gsum[b * 256 + t] = s;
}

// ---------------- kernel 4: finalize (tiny, 43 KB in) ----------------
__global__ __launch_bounds__(256) void k_final2(const float* __restrict__ gsum,
                                                const float* __restrict__ gcnt,
                                                float* __restrict__ out)
{
    __shared__ float anc[NUMC * 260];
    __shared__ float con[NUMC * 260];
    __shared__ float adc[NUMC * 44];
    __shared__ float cntS[NUMC];
    __shared__ float rowloss[NUMC];
    __shared__ float rowvalid[NUMC];

    if (threadIdx.x < NUMC) cntS[threadIdx.x] = gcnt[threadIdx.x];
    __syncthreads();
    for (int i = threadIdx.x; i < KC; i += 256) {
        int k = i >> 8, c = i & 255;
        float cn = cntS[k];
        bool pr = cn > 0.f;
        float d = pr ? cn : 1.f;
        anc[k * 260 + c] = pr ? gsum[k * 256 + c] / d : 0.f;
        con[k * 260 + c] = pr ? gsum[(NUMC + k) * 256 + c] / d : 0.f;
    }
    __syncthreads();
    // adc[k][j] = dot(anc_k, contrast_j)/T,  contrast = [anc; con]
    for (int pair = threadIdx.x; pair < NUMC * 2 * NUMC; pair += 256) {
        int k = pair / (2 * NUMC);
        int j = pair % (2 * NUMC);
        const float* ar = anc + k * 260;
        const float* br = (j < NUMC) ? (anc + j * 260) : (con + (j - NUMC) * 260);
        float s = 0.f;
        for (int c = 0; c < CCH; c += 4) {
            float4 a4 = *(const float4*)(ar + c);
            float4 b4 = *(const float4*)(br + c);
            s += a4.x * b4.x + a4.y * b4.y + a4.z * b4.z + a4.w * b4.w;
        }
        adc[k * 44 + j] = s / 0.07f;
    }
    __syncthreads();
    if (threadIdx.x < NUMC) {
        int k = threadIdx.x;
        bool pr = cntS[k] > 0.f;
        float neg = 0.f;       // faithful to source — negatives use UNshifted logits
        float mx = -1e30f;
        for (int j = 0; j < 2 * NUMC; ++j) {
            int cj = (j < NUMC) ? j : (j - NUMC);
            bool cp = cntS[cj] > 0.f;
            float v = adc[k * 44 + j];
            if (cp) {
                if (v > mx) mx = v;
                if (j != k && j != NUMC + k) neg += expf(v);
            }
        }
        float sh = adc[k * 44 + NUMC + k] - mx;
        float rl = -(sh - logf(expf(sh) + neg));
        rowloss[k] = pr ? rl : 0.f;
        rowvalid[k] = pr ? 1.f : 0.f;
    }
    __syncthreads();
    if (threadIdx.x == 0) {
        float s = 0.f, v = 0.f;
        for (int kk = 0; kk < NUMC; ++kk) { s += rowloss[kk]; v += rowvalid[kk]; }
        out[0] = s / fmaxf(v, 1.f);
    }
}

// ---------------- launch ----------------
extern "C" void kernel_launch(void* const* d_in, const int* in_sizes, int n_in,
                              void* d_out, int out_size, void* d_ws, size_t ws_size,
                              hipStream_t stream) {
    const int*   labels      = (const int*)  d_in[0];
    const float* feats_old   = (const float*)d_in[1];
    const float* feats       = (const float*)d_in[2];
    const float* outputs_old = (const float*)d_in[3];
    // d_in[4] (outputs) and d_in[5] (prototypes) are unused by the reference math.

    float* ws    = (float*)d_ws;
    int*   lab   = (int*)ws;                   // [131072]
    float* partA = ws + 131072;                // [16*5376]
    float* partO = partA + NREP * KC;          // [16*5376]
    float* gcnt  = partO + NREP * KC;          // [21]
    float* gsum  = gcnt + 32;                  // [42*256]

    hipMemsetAsync(partA, 0, (size_t)(2 * NREP * KC + NUMC) * sizeof(float), stream);

    k_labels<<<NPIX / 256, 256, 0, stream>>>(labels, outputs_old, lab, gcnt);
    k_msum  <<<1024, 256, 0, stream>>>(feats, feats_old, lab, partA, partO);
    k_red   <<<42, 256, 0, stream>>>(partA, partO, gsum);
    k_final2<<<1, 256, 0, stream>>>(gsum, gcnt, (float*)d_out);
}